// Round 1
// baseline (33.379 us; speedup 1.0000x reference)
//
#include <hip/hip_runtime.h>

// Basket embedding mean-pool.
// item_ids: [B, L, M] int32; basket_lens: [B, L] int32; emb: [VOCAB, H] f32
// out: [B, L, H] f32 ; out[b,l,:] = sum_{m<len} emb[ids[b,l,m]] / max(len,1)

constexpr int Bn = 1024, Ln = 50, Mn = 20, Hn = 64;
constexpr int NB = Bn * Ln;                 // 51200 baskets
constexpr int LANES_PER_BASKET = 16;        // each lane owns 4 h-channels (float4)

__global__ __launch_bounds__(256) void basket_pool_kernel(
    const int* __restrict__ item_ids,       // [NB, M]
    const int* __restrict__ basket_lens,    // [NB]
    const float* __restrict__ emb,          // [VOCAB, H]
    float* __restrict__ out)                // [NB, H]
{
    const int tid    = blockIdx.x * blockDim.x + threadIdx.x;
    const int basket = tid >> 4;            // 16 lanes per basket
    const int lane   = tid & 15;            // h = lane*4 .. lane*4+3
    if (basket >= NB) return;

    const int len = basket_lens[basket];
    const int* __restrict__ ids = item_ids + basket * Mn;

    float4 acc = make_float4(0.f, 0.f, 0.f, 0.f);
    for (int m = 0; m < len; ++m) {
        const int id = ids[m];
        const float4 v = *reinterpret_cast<const float4*>(
            emb + (size_t)id * Hn + lane * 4);
        acc.x += v.x; acc.y += v.y; acc.z += v.z; acc.w += v.w;
    }
    const float inv = 1.0f / (float)(len > 0 ? len : 1);
    acc.x *= inv; acc.y *= inv; acc.z *= inv; acc.w *= inv;

    *reinterpret_cast<float4*>(out + (size_t)basket * Hn + lane * 4) = acc;
}

extern "C" void kernel_launch(void* const* d_in, const int* in_sizes, int n_in,
                              void* d_out, int out_size, void* d_ws, size_t ws_size,
                              hipStream_t stream) {
    const int*   item_ids    = (const int*)d_in[0];    // B*L*M
    const int*   basket_lens = (const int*)d_in[1];    // B*L
    const float* emb         = (const float*)d_in[2];  // VOCAB*H
    float*       out         = (float*)d_out;          // B*L*H

    const int total_threads = NB * LANES_PER_BASKET;   // 819200
    const int block = 256;
    const int grid  = (total_threads + block - 1) / block;  // 3200
    basket_pool_kernel<<<grid, block, 0, stream>>>(item_ids, basket_lens, emb, out);
}

// Round 2
// 25.329 us; speedup vs baseline: 1.3178x; 1.3178x over previous
//
#include <hip/hip_runtime.h>

// Basket embedding mean-pool.
// item_ids: [B, L, M] int32; basket_lens: [B, L] int32; emb: [VOCAB, H] f32
// out: [B, L, H] f32 ; out[b,l,:] = sum_{m<len} emb[ids[b,l,m]] / max(len,1)
//
// R2: latency-bound fix — preload all 20 ids, fully unroll the gather with
// compile-time register indexing, issue all 20 float4 gathers in flight
// (select id0 for m>=len: same segment as m=0's load -> L1 hit, no extra
// HBM/L2 traffic), masked-FMA accumulate.

constexpr int Bn = 1024, Ln = 50, Mn = 20, Hn = 64;
constexpr int NB = Bn * Ln;                 // 51200 baskets

__global__ __launch_bounds__(256) void basket_pool_kernel(
    const int* __restrict__ item_ids,       // [NB, M]
    const int* __restrict__ basket_lens,    // [NB]
    const float* __restrict__ emb,          // [VOCAB, H]
    float* __restrict__ out)                // [NB, H]
{
    const int tid    = blockIdx.x * blockDim.x + threadIdx.x;
    const int basket = tid >> 4;            // 16 lanes per basket
    const int lane   = tid & 15;            // h = lane*4 .. lane*4+3
    if (basket >= NB) return;

    const int len = basket_lens[basket];
    const int* __restrict__ ids = item_ids + basket * Mn;

    // ---- preload all 20 ids (5x int4; 16 lanes read same addrs -> one
    // coalesced transaction per group) ----
    int idbuf[Mn];
#pragma unroll
    for (int c = 0; c < Mn / 4; ++c) {
        const int4 t = reinterpret_cast<const int4*>(ids)[c];
        idbuf[c * 4 + 0] = t.x;
        idbuf[c * 4 + 1] = t.y;
        idbuf[c * 4 + 2] = t.z;
        idbuf[c * 4 + 3] = t.w;
    }
    const int id0 = idbuf[0];

    // ---- resolve effective ids (compile-time indices only -> registers) ----
    int eid[Mn];
#pragma unroll
    for (int m = 0; m < Mn; ++m)
        eid[m] = (m < len) ? idbuf[m] : id0;   // id0 slot -> L1 hit, masked out

    // ---- issue all 20 gathers (independent; max MLP) ----
    const float* __restrict__ embp = emb + (size_t)lane * 4;
    float4 v[Mn];
#pragma unroll
    for (int m = 0; m < Mn; ++m)
        v[m] = *reinterpret_cast<const float4*>(embp + (size_t)eid[m] * Hn);

    // ---- masked accumulate, 2 chains ----
    float4 acc0 = make_float4(0.f, 0.f, 0.f, 0.f);
    float4 acc1 = make_float4(0.f, 0.f, 0.f, 0.f);
#pragma unroll
    for (int m = 0; m < Mn; m += 2) {
        const float wa = (m < len) ? 1.f : 0.f;
        acc0.x = fmaf(v[m].x, wa, acc0.x);
        acc0.y = fmaf(v[m].y, wa, acc0.y);
        acc0.z = fmaf(v[m].z, wa, acc0.z);
        acc0.w = fmaf(v[m].w, wa, acc0.w);
        const float wb = (m + 1 < len) ? 1.f : 0.f;
        acc1.x = fmaf(v[m + 1].x, wb, acc1.x);
        acc1.y = fmaf(v[m + 1].y, wb, acc1.y);
        acc1.z = fmaf(v[m + 1].z, wb, acc1.z);
        acc1.w = fmaf(v[m + 1].w, wb, acc1.w);
    }

    const float inv = 1.0f / (float)(len > 0 ? len : 1);
    float4 r;
    r.x = (acc0.x + acc1.x) * inv;
    r.y = (acc0.y + acc1.y) * inv;
    r.z = (acc0.z + acc1.z) * inv;
    r.w = (acc0.w + acc1.w) * inv;

    *reinterpret_cast<float4*>(out + (size_t)basket * Hn + lane * 4) = r;
}

extern "C" void kernel_launch(void* const* d_in, const int* in_sizes, int n_in,
                              void* d_out, int out_size, void* d_ws, size_t ws_size,
                              hipStream_t stream) {
    const int*   item_ids    = (const int*)d_in[0];    // B*L*M
    const int*   basket_lens = (const int*)d_in[1];    // B*L
    const float* emb         = (const float*)d_in[2];  // VOCAB*H
    float*       out         = (float*)d_out;          // B*L*H

    const int total_threads = NB * 16;                 // 819200
    const int block = 256;
    const int grid  = (total_threads + block - 1) / block;  // 3200
    basket_pool_kernel<<<grid, block, 0, stream>>>(item_ids, basket_lens, emb, out);
}

// Round 3
// 24.809 us; speedup vs baseline: 1.3454x; 1.0209x over previous
//
#include <hip/hip_runtime.h>

// Basket embedding mean-pool.
// item_ids: [B, L, M] int32; basket_lens: [B, L] int32; emb: [VOCAB, H] f32
// out: [B, L, H] f32 ; out[b,l,:] = sum_{m<len} emb[ids[b,l,m]] / max(len,1)
//
// R3: ring-8 software pipeline. R2 held 20 float4 loads live (VGPR>128 ->
// 2-3 waves/SIMD, not enough in-flight loads to cover LLC gather latency).
// Ring keeps 8 gathers in flight with ~1/3 the registers; launch_bounds
// (256,4) pins >=4 waves/SIMD. Padded slots (m>=len) load id0's line
// (MSHR-merge/L1 hit, masked out of the accumulate). 32-bit address math.

constexpr int Bn = 1024, Ln = 50, Mn = 20, Hn = 64;
constexpr int NB = Bn * Ln;                 // 51200 baskets
constexpr int RING = 8;

__global__ __launch_bounds__(256, 4) void basket_pool_kernel(
    const int* __restrict__ item_ids,       // [NB, M]
    const int* __restrict__ basket_lens,    // [NB]
    const float* __restrict__ emb,          // [VOCAB, H]
    float* __restrict__ out)                // [NB, H]
{
    const int tid    = blockIdx.x * blockDim.x + threadIdx.x;
    const int basket = tid >> 4;            // 16 lanes per basket
    const int lane4  = (tid & 15) << 2;     // h offset: lane*4
    if (basket >= NB) return;

    const int len = basket_lens[basket];
    const int* __restrict__ ids = item_ids + basket * Mn;

    // preload all 20 ids (5x int4, coalesced within each 16-lane group)
    int idb[Mn];
#pragma unroll
    for (int c = 0; c < Mn / 4; ++c) {
        const int4 t = reinterpret_cast<const int4*>(ids)[c];
        idb[c * 4 + 0] = t.x;
        idb[c * 4 + 1] = t.y;
        idb[c * 4 + 2] = t.z;
        idb[c * 4 + 3] = t.w;
    }
    const int id0 = idb[0];

    // ring of in-flight gathers (all indices compile-time after unroll)
    float4 v[RING];
#pragma unroll
    for (int m = 0; m < RING; ++m) {
        const int e = (m < len) ? idb[m] : id0;          // in-bounds always
        v[m] = *reinterpret_cast<const float4*>(emb + (e * Hn + lane4));
    }

    float4 acc0 = make_float4(0.f, 0.f, 0.f, 0.f);
    float4 acc1 = make_float4(0.f, 0.f, 0.f, 0.f);
#pragma unroll
    for (int m = 0; m < Mn; ++m) {
        const float4 x = v[m % RING];                     // consume
        if (m + RING < Mn) {                              // refill slot
            const int e = (m + RING < len) ? idb[m + RING] : id0;
            v[m % RING] = *reinterpret_cast<const float4*>(emb + (e * Hn + lane4));
        }
        const float w = (m < len) ? 1.f : 0.f;
        if (m & 1) {
            acc1.x = fmaf(x.x, w, acc1.x);
            acc1.y = fmaf(x.y, w, acc1.y);
            acc1.z = fmaf(x.z, w, acc1.z);
            acc1.w = fmaf(x.w, w, acc1.w);
        } else {
            acc0.x = fmaf(x.x, w, acc0.x);
            acc0.y = fmaf(x.y, w, acc0.y);
            acc0.z = fmaf(x.z, w, acc0.z);
            acc0.w = fmaf(x.w, w, acc0.w);
        }
    }

    const float inv = 1.0f / (float)(len > 0 ? len : 1);
    float4 r;
    r.x = (acc0.x + acc1.x) * inv;
    r.y = (acc0.y + acc1.y) * inv;
    r.z = (acc0.z + acc1.z) * inv;
    r.w = (acc0.w + acc1.w) * inv;

    *reinterpret_cast<float4*>(out + (basket * Hn + lane4)) = r;
}

extern "C" void kernel_launch(void* const* d_in, const int* in_sizes, int n_in,
                              void* d_out, int out_size, void* d_ws, size_t ws_size,
                              hipStream_t stream) {
    const int*   item_ids    = (const int*)d_in[0];    // B*L*M
    const int*   basket_lens = (const int*)d_in[1];    // B*L
    const float* emb         = (const float*)d_in[2];  // VOCAB*H
    float*       out         = (float*)d_out;          // B*L*H

    const int total_threads = NB * 16;                 // 819200
    const int block = 256;
    const int grid  = (total_threads + block - 1) / block;  // 3200
    basket_pool_kernel<<<grid, block, 0, stream>>>(item_ids, basket_lens, emb, out);
}